// Round 16
// baseline (208.474 us; speedup 1.0000x reference)
//
#include <hip/hip_runtime.h>
#include <hip/hip_bf16.h>
#include <math.h>

typedef float floatx4 __attribute__((ext_vector_type(4)));
typedef short short8 __attribute__((ext_vector_type(8)));

#define IN_DIM 128
#define OUT_DIM 64
#define OWNER(d) (((d) >> 4) & 7)   // fallback-scatter XCD ownership
#define CHUNK 2048                   // fallback scatter chunk
#define CAP 32        // ssort slots/node; P(Poisson(16)>32) ~ 2e-4
#define OVF_CAP 8192  // exact overflow path
#define WPAD 136      // ushort row stride for W in LDS (gemm)
// R7/R8: binning beats atomic scatter. R12: NBIN=512 (2 blocks/CU) WON.
// R13-R15: k_node is L3-latency-exposed on the random z gather; MLP depth
// is the lever (2->4 loads: 67.6->64us). This round: single-pass gather,
// wave-uniform branch deg<=16 ? 4 : 8 loads all in flight (deg<=CAP=32).
// FMA order identical to R15 -> bitwise-identical output.
#define NBIN 512
#define NB_SHIFT 8
#define CELL_CAP 18
#define SPILL_BIT (1 << 20)

__device__ __forceinline__ unsigned short bf16_rne(float f) {
    unsigned u = __float_as_uint(f);
    u += 0x7FFFu + ((u >> 16) & 1u);
    return (unsigned short)(u >> 16);
}
__device__ __forceinline__ float bf16_tof(unsigned short b) {
    return __uint_as_float(((unsigned)b) << 16);
}

// ---------------------------------------------------------------------------
// MFMA GEMM (R5-exact, verified absmax 0.00390625): split-precision
// z = h@W^T via mfma_f32_16x16x32_bf16. Prologue zeroes meta (cursor|ovfcnt)
// -- safe: k_bin runs strictly after in stream order (separate dispatch).
// ---------------------------------------------------------------------------
__global__ __launch_bounds__(256) void k_gemm(
    const float* __restrict__ h, const float* __restrict__ W,
    const float* __restrict__ a, __hip_bfloat16* __restrict__ z,
    float* __restrict__ s_src, float* __restrict__ s_dst, int N,
    int* __restrict__ meta, int mcount)
{
    __shared__ __align__(16) unsigned short sWhi[64 * WPAD];
    __shared__ __align__(16) unsigned short sWlo[64 * WPAD];

    const int tid = threadIdx.x;
    for (int i = blockIdx.x * 256 + tid; i < mcount; i += gridDim.x * 256)
        meta[i] = 0;

#pragma unroll
    for (int i = 0; i < 32; ++i) {
        int g = tid + 256 * i;            // 0..8191
        float f = W[g];
        int row = g >> 7, k = g & 127;
        unsigned short hb = bf16_rne(f);
        sWhi[row * WPAD + k] = hb;
        sWlo[row * WPAD + k] = bf16_rne(f - bf16_tof(hb));
    }

    const int wave = tid >> 6;
    const int l = tid & 63;
    const int lr = l & 15;                // A/B row-in-tile; C/D col
    const int lk = l >> 4;                // k-group / C/D row-group
    const int n0w = blockIdx.x * 64 + wave * 16;

    const int arow = min(n0w + lr, N - 1);   // clamp: garbage rows never stored
    const float* hrow = h + (size_t)arow * IN_DIM;
    short8 ahi[4], alo[4];
#pragma unroll
    for (int ks = 0; ks < 4; ++ks) {
        int k0 = 32 * ks + 8 * lk;
        floatx4 f0 = *(const floatx4*)(hrow + k0);
        floatx4 f1 = *(const floatx4*)(hrow + k0 + 4);
        float fv[8] = {f0.x, f0.y, f0.z, f0.w, f1.x, f1.y, f1.z, f1.w};
#pragma unroll
        for (int j = 0; j < 8; ++j) {
            unsigned short hb = bf16_rne(fv[j]);
            ahi[ks][j] = (short)hb;
            alo[ks][j] = (short)bf16_rne(fv[j] - bf16_tof(hb));
        }
    }
    __syncthreads();

    float ps[4] = {0.f, 0.f, 0.f, 0.f};
    float pd[4] = {0.f, 0.f, 0.f, 0.f};
#pragma unroll
    for (int ct = 0; ct < 4; ++ct) {
        floatx4 acc = (floatx4){0.f, 0.f, 0.f, 0.f};
#pragma unroll
        for (int ks = 0; ks < 4; ++ks) {
            const int boff = (ct * 16 + lr) * WPAD + 32 * ks + 8 * lk;
            short8 bhi = *(const short8*)&sWhi[boff];
            short8 blo = *(const short8*)&sWlo[boff];
            acc = __builtin_amdgcn_mfma_f32_16x16x32_bf16(ahi[ks], bhi, acc, 0, 0, 0);
            acc = __builtin_amdgcn_mfma_f32_16x16x32_bf16(alo[ks], bhi, acc, 0, 0, 0);
            acc = __builtin_amdgcn_mfma_f32_16x16x32_bf16(ahi[ks], blo, acc, 0, 0, 0);
        }
        const float asv = a[ct * 16 + lr];
        const float adv = a[OUT_DIM + ct * 16 + lr];
#pragma unroll
        for (int r = 0; r < 4; ++r) {
            int n = n0w + lk * 4 + r;
            if (n < N)
                z[(size_t)n * OUT_DIM + ct * 16 + lr] = __float2bfloat16(acc[r]);
            ps[r] += acc[r] * asv;
            pd[r] += acc[r] * adv;
        }
    }
#pragma unroll
    for (int r = 0; r < 4; ++r) {
#pragma unroll
        for (int off = 1; off <= 8; off <<= 1) {
            ps[r] += __shfl_xor(ps[r], off);
            pd[r] += __shfl_xor(pd[r], off);
        }
        int n = n0w + lk * 4 + r;
        if (lr == 0 && n < N) {
            s_src[n] = ps[r];
            s_dst[n] = pd[r];
        }
    }
}

// ---------------------------------------------------------------------------
// Phase 1: single-scan LDS binning (R8-proven body; R12: grid=512 WON).
// ---------------------------------------------------------------------------
__global__ __launch_bounds__(256) void k_bin(
    const int* __restrict__ src, const int* __restrict__ dst,
    int* __restrict__ cursor, unsigned* __restrict__ bdata,
    int* __restrict__ bcnt, int* __restrict__ ovfcnt,
    int2* __restrict__ ovf, int E, int NB, int epb)
{
    __shared__ int cell[512];
    const int tid = threadIdx.x;
    for (int i = tid; i < NB; i += 256) cell[i] = 0;
    __syncthreads();

    const int c = blockIdx.x;
    const int e0 = c * epb;
    const int e1 = min(e0 + epb, E);
    const size_t cbase = (size_t)c * NB * CELL_CAP;
    for (int e = e0 + tid; e < e1; e += 256) {
        int d = __builtin_nontemporal_load(&dst[e]);
        int s = __builtin_nontemporal_load(&src[e]);
        int b = d >> NB_SHIFT;
        int slot = atomicAdd(&cell[b], 1);
        if (slot < CELL_CAP) {
            bdata[cbase + (size_t)b * CELL_CAP + slot] =
                ((unsigned)s << NB_SHIFT) |
                (unsigned)(d & ((1 << NB_SHIFT) - 1));
        } else {
            atomicAdd(&cursor[d], SPILL_BIT);
            int op = atomicAdd(ovfcnt, 1);
            if (op < OVF_CAP) ovf[op] = make_int2(s, d);
        }
    }
    __syncthreads();
    for (int b = tid; b < NB; b += 256) bcnt[c * NB + b] = cell[b];
}

// ---------------------------------------------------------------------------
// Phase 2: one block per bucket = sole owner of 256 contiguous nodes (R8).
// ---------------------------------------------------------------------------
__global__ __launch_bounds__(256) void k_fill(
    const unsigned* __restrict__ bdata, const int* __restrict__ bcnt,
    int* __restrict__ cursor, int* __restrict__ ssort,
    int* __restrict__ ovfcnt, int2* __restrict__ ovf,
    int nb1, int NB, int N)
{
    __shared__ int lcur[256];
    const int tid = threadIdx.x;
    lcur[tid] = 0;
    __syncthreads();

    const int b = blockIdx.x;
    const int n0 = b << NB_SHIFT;
    for (int c = tid; c < nb1; c += 256) {
        int cnt = min(bcnt[c * NB + b], CELL_CAP);
        size_t base = ((size_t)c * NB + b) * CELL_CAP;
        for (int j = 0; j < cnt; ++j) {
            unsigned v = bdata[base + j];
            int i = (int)(v & ((1u << NB_SHIFT) - 1));
            int s = (int)(v >> NB_SHIFT);
            int slot = atomicAdd(&lcur[i], 1);
            if (slot < CAP) {
                ssort[(n0 + i) * CAP + slot] = s;
            } else {
                int op = atomicAdd(ovfcnt, 1);
                if (op < OVF_CAP) ovf[op] = make_int2(s, n0 + i);
            }
        }
    }
    __syncthreads();
    int n = n0 + tid;
    if (n < N) {
        int v = lcur[tid];
        if (v) cursor[n] += v;    // sole owner; spill bits preserved
    }
}

// ---------------------------------------------------------------------------
// Fallback scatter (proven R0 82us body) for small workspaces.
// ---------------------------------------------------------------------------
__global__ __launch_bounds__(256) void k_scatter(
    const int* __restrict__ src, const int* __restrict__ dst,
    int* __restrict__ cursor, int* __restrict__ ssort,
    int* __restrict__ ovfcnt, int2* __restrict__ ovf, int E)
{
    const int x = blockIdx.x & 7;
    const int c = blockIdx.x >> 3;
    const int e0 = c * CHUNK;
#pragma unroll
    for (int i = 0; i < CHUNK / 256; ++i) {
        int e = e0 + i * 256 + threadIdx.x;
        if (e < E) {
            int d = __builtin_nontemporal_load(&dst[e]);
            if (OWNER(d) == x) {
                int s = __builtin_nontemporal_load(&src[e]);
                int pos = atomicAdd(&cursor[d], 1);
                if (pos < CAP) {
                    ssort[d * CAP + pos] = s;
                } else {
                    int op = atomicAdd(ovfcnt, 1);
                    if (op < OVF_CAP) ovf[op] = make_int2(s, d);
                }
            }
        }
    }
}

// ---------------------------------------------------------------------------
// Fused per-node softmax + weighted gather + ELU. Single-pass gather:
// wave-uniform branch (deg is per-wave) picks 4 or 8 z-row loads, ALL in
// flight before any FMA. Sub-loops (shfl/pred -> loads -> FMA) with
// static-indexed register arrays. Per-lane FMA order == R15 -> bitwise
// identical. Predication kept (R12: it is the load-ILP scaffolding).
// ---------------------------------------------------------------------------
__global__ __launch_bounds__(256) void k_node(
    const int* __restrict__ cursor, const int* __restrict__ ssort,
    const float* __restrict__ s_src, const float* __restrict__ s_dst,
    const int* __restrict__ ovfcnt, const int2* __restrict__ ovf,
    const __hip_bfloat16* __restrict__ z, float* __restrict__ out, int N)
{
    const int lane = threadIdx.x & 63;
    const int wave = threadIdx.x >> 6;
    const int n = blockIdx.x * 4 + wave;
    if (n >= N) return;

    const int lg = lane >> 4;             // edge subgroup 0..3
    const int lc = lane & 15;             // col group: cols 4lc..4lc+3

    const int raw = cursor[n];
    if (raw == 0) {                       // empty segment -> elu(0) = 0
        if (lg == 0) {
            floatx4 zero = (floatx4){0.f, 0.f, 0.f, 0.f};
            __builtin_nontemporal_store(zero, (floatx4*)&out[(size_t)n * OUT_DIM + 4 * lc]);
        }
        return;
    }
    const int low = raw & 0xFFFFF;
    const int deg = min(low, CAP);
    const int base = n * CAP;
    const float sdn = s_dst[n];

    // score phase: lane kk handles edge kk (deg <= 32 < 64: single pass)
    float sum = 0.f;
    int sv = 0;
    float ev = 0.f;
    {
        int kk = lane;
        if (kk < deg) {
            sv = __builtin_nontemporal_load(&ssort[base + kk]);
            float sc = s_src[sv] + sdn;
            sc = sc > 0.f ? sc : 0.01f * sc;   // leaky_relu
            ev = __expf(sc);
        }
        sum += ev;
    }

    // gather: single pass, all loads in flight (4 slots if deg<=16, else 8)
    floatx4 acc = (floatx4){0.f, 0.f, 0.f, 0.f};
    if (deg <= 16) {
        int sa[4]; float w[4];
#pragma unroll
        for (int u = 0; u < 4; ++u) {
            int jj = 4 * u + lg;
            bool ok = jj < deg;
            int s = __shfl(sv, ok ? jj : 0);
            float ww = __shfl(ev, ok ? jj : 0);
            w[u] = ok ? ww : 0.f;
            sa[u] = ok ? s : 0;
        }
        uint2 v[4];
#pragma unroll
        for (int u = 0; u < 4; ++u)
            v[u] = *(const uint2*)&z[(size_t)sa[u] * OUT_DIM + 4 * lc];
#pragma unroll
        for (int u = 0; u < 4; ++u) {
            acc.x += w[u] * __uint_as_float(v[u].x << 16);
            acc.y += w[u] * __uint_as_float(v[u].x & 0xFFFF0000u);
            acc.z += w[u] * __uint_as_float(v[u].y << 16);
            acc.w += w[u] * __uint_as_float(v[u].y & 0xFFFF0000u);
        }
    } else {
        int sa[8]; float w[8];
#pragma unroll
        for (int u = 0; u < 8; ++u) {
            int jj = 4 * u + lg;
            bool ok = jj < deg;
            int s = __shfl(sv, ok ? jj : 0);
            float ww = __shfl(ev, ok ? jj : 0);
            w[u] = ok ? ww : 0.f;
            sa[u] = ok ? s : 0;
        }
        uint2 v[8];
#pragma unroll
        for (int u = 0; u < 8; ++u)
            v[u] = *(const uint2*)&z[(size_t)sa[u] * OUT_DIM + 4 * lc];
#pragma unroll
        for (int u = 0; u < 8; ++u) {
            acc.x += w[u] * __uint_as_float(v[u].x << 16);
            acc.y += w[u] * __uint_as_float(v[u].x & 0xFFFF0000u);
            acc.z += w[u] * __uint_as_float(v[u].y << 16);
            acc.w += w[u] * __uint_as_float(v[u].y & 0xFFFF0000u);
        }
    }
    // fold the 4 edge subgroups: lanes sharing lc end with identical acc
    acc.x += __shfl_xor(acc.x, 16); acc.y += __shfl_xor(acc.y, 16);
    acc.z += __shfl_xor(acc.z, 16); acc.w += __shfl_xor(acc.w, 16);
    acc.x += __shfl_xor(acc.x, 32); acc.y += __shfl_xor(acc.y, 32);
    acc.z += __shfl_xor(acc.z, 32); acc.w += __shfl_xor(acc.w, 32);

    // exact overflow path (after fold: all lg-redundant lanes add identically)
    if (raw > CAP) {
        int oc = min(*ovfcnt, OVF_CAP);
        for (int i = 0; i < oc; ++i) {
            int2 p = ovf[i];
            if (p.y == n) {
                float sc = s_src[p.x] + sdn;
                sc = sc > 0.f ? sc : 0.01f * sc;
                float e2 = __expf(sc);
                if (lane == 0) sum += e2;
                uint2 v = *(const uint2*)&z[(size_t)p.x * OUT_DIM + 4 * lc];
                acc.x += e2 * __uint_as_float(v.x << 16);
                acc.y += e2 * __uint_as_float(v.x & 0xFFFF0000u);
                acc.z += e2 * __uint_as_float(v.y << 16);
                acc.w += e2 * __uint_as_float(v.y & 0xFFFF0000u);
            }
        }
    }

#pragma unroll
    for (int off = 32; off >= 1; off >>= 1) sum += __shfl_xor(sum, off);

    if (lg == 0) {
        float inv = 1.f / sum;
        floatx4 o;
        o.x = acc.x * inv; o.y = acc.y * inv;
        o.z = acc.z * inv; o.w = acc.w * inv;
        o.x = o.x > 0.f ? o.x : __expf(o.x) - 1.f;   // ELU, alpha=1
        o.y = o.y > 0.f ? o.y : __expf(o.y) - 1.f;
        o.z = o.z > 0.f ? o.z : __expf(o.z) - 1.f;
        o.w = o.w > 0.f ? o.w : __expf(o.w) - 1.f;
        __builtin_nontemporal_store(o, (floatx4*)&out[(size_t)n * OUT_DIM + 4 * lc]);
    }
}

// ---------------------------------------------------------------------------
extern "C" void kernel_launch(void* const* d_in, const int* in_sizes, int n_in,
                              void* d_out, int out_size, void* d_ws, size_t ws_size,
                              hipStream_t stream)
{
    (void)n_in; (void)out_size;

    const float* h  = (const float*)d_in[0];
    const int* src  = (const int*)d_in[1];
    const int* dst  = (const int*)d_in[2];
    const float* W  = (const float*)d_in[3];
    const float* a  = (const float*)d_in[4];
    const int N = in_sizes[0] / IN_DIM;
    const int E = in_sizes[1];
    float* out = (float*)d_out;

    const int NB  = (N + (1 << NB_SHIFT) - 1) >> NB_SHIFT;
    const int nb1 = NBIN;                       // 512 = exactly 2 blocks/CU
    const int epb = (E + NBIN - 1) / NBIN;      // edges per bin block

    auto rnd = [](size_t b) { return (b + 255) & ~(size_t)255; };
    // meta: cursor[N] | ovfcnt | bcnt[nb1*NB]  (bcnt fully overwritten by k_bin)
    const size_t meta_ints = (size_t)N + 1 + (size_t)nb1 * NB;
    const size_t need_bucket =
        rnd((size_t)N * OUT_DIM * 2) + 2 * rnd((size_t)N * 4) +
        rnd(meta_ints * 4) + rnd((size_t)OVF_CAP * 8) +
        rnd((size_t)N * CAP * 4) + rnd((size_t)nb1 * NB * CELL_CAP * 4);
    const bool bucketed = (NB <= 512) && (need_bucket <= ws_size);

    char* wsp = (char*)d_ws;
    size_t off = 0;
    auto alloc = [&](size_t bytes) -> void* {
        void* p = wsp + off;
        off = (off + bytes + 255) & ~(size_t)255;
        return p;
    };
    __hip_bfloat16* z = (__hip_bfloat16*)alloc((size_t)N * OUT_DIM * 2);
    float* s_src = (float*)alloc((size_t)N * 4);
    float* s_dst = (float*)alloc((size_t)N * 4);

    if (bucketed) {
        int* cursor = (int*)alloc(meta_ints * 4);
        int* ovfcnt = cursor + N;
        int* bcnt   = cursor + N + 1;
        int2* ovf   = (int2*)alloc((size_t)OVF_CAP * 8);
        int* ssort  = (int*)alloc((size_t)N * CAP * 4);
        unsigned* bdata = (unsigned*)alloc((size_t)nb1 * NB * CELL_CAP * 4);

        // gemm zeroes cursor|ovfcnt (N+1 ints); bcnt fully overwritten by k_bin
        k_gemm<<<(N + 63) / 64, 256, 0, stream>>>(h, W, a, z, s_src, s_dst, N,
                                                  cursor, N + 1);
        k_bin<<<nb1, 256, 0, stream>>>(src, dst, cursor, bdata, bcnt,
                                       ovfcnt, ovf, E, NB, epb);
        k_fill<<<NB, 256, 0, stream>>>(bdata, bcnt, cursor, ssort,
                                       ovfcnt, ovf, nb1, NB, N);
        k_node<<<(N + 3) / 4, 256, 0, stream>>>(cursor, ssort, s_src, s_dst,
                                                ovfcnt, ovf, z, out, N);
    } else {
        int* cursor = (int*)alloc((size_t)(N + 1) * 4);
        int* ovfcnt = cursor + N;
        int2* ovf   = (int2*)alloc((size_t)OVF_CAP * 8);
        int* ssort  = (int*)alloc((size_t)N * CAP * 4);

        const int nchunks = (E + CHUNK - 1) / CHUNK;
        k_gemm<<<(N + 63) / 64, 256, 0, stream>>>(h, W, a, z, s_src, s_dst, N,
                                                  cursor, N + 1);
        k_scatter<<<nchunks * 8, 256, 0, stream>>>(src, dst, cursor, ssort,
                                                   ovfcnt, ovf, E);
        k_node<<<(N + 3) / 4, 256, 0, stream>>>(cursor, ssort, s_src, s_dst,
                                                ovfcnt, ovf, z, out, N);
    }
}

// Round 17
// 200.974 us; speedup vs baseline: 1.0373x; 1.0373x over previous
//
#include <hip/hip_runtime.h>
#include <hip/hip_bf16.h>
#include <math.h>

typedef float floatx4 __attribute__((ext_vector_type(4)));
typedef short short8 __attribute__((ext_vector_type(8)));

#define IN_DIM 128
#define OUT_DIM 64
#define OWNER(d) (((d) >> 4) & 7)   // fallback-scatter XCD ownership
#define CHUNK 2048                   // fallback scatter chunk
#define CAP 32        // ssort slots/node; P(Poisson(16)>32) ~ 2e-4
#define OVF_CAP 8192  // exact overflow path
#define WPAD 136      // ushort row stride for W in LDS (gemm)
// R7/R8: binning beats atomic scatter. R12: NBIN=512 WON. R13-R16: k_node
// is latency-bound; within-gather MLP saturated at depth 4 (R16 null at 8).
// This round: 2 nodes per wave (32-lane halves) -- every serial wait point
// (cursor/ssort/s_src/exp) serves 2 nodes, nodes-in-flight doubles, and the
// score phase uses all 64 lanes (was <=32).
#define NBIN 512
#define NB_SHIFT 8
#define CELL_CAP 18
#define SPILL_BIT (1 << 20)

__device__ __forceinline__ unsigned short bf16_rne(float f) {
    unsigned u = __float_as_uint(f);
    u += 0x7FFFu + ((u >> 16) & 1u);
    return (unsigned short)(u >> 16);
}
__device__ __forceinline__ float bf16_tof(unsigned short b) {
    return __uint_as_float(((unsigned)b) << 16);
}

// ---------------------------------------------------------------------------
// MFMA GEMM (R5-exact, verified absmax 0.00390625): split-precision
// z = h@W^T via mfma_f32_16x16x32_bf16. Prologue zeroes meta (cursor|ovfcnt).
// ---------------------------------------------------------------------------
__global__ __launch_bounds__(256) void k_gemm(
    const float* __restrict__ h, const float* __restrict__ W,
    const float* __restrict__ a, __hip_bfloat16* __restrict__ z,
    float* __restrict__ s_src, float* __restrict__ s_dst, int N,
    int* __restrict__ meta, int mcount)
{
    __shared__ __align__(16) unsigned short sWhi[64 * WPAD];
    __shared__ __align__(16) unsigned short sWlo[64 * WPAD];

    const int tid = threadIdx.x;
    for (int i = blockIdx.x * 256 + tid; i < mcount; i += gridDim.x * 256)
        meta[i] = 0;

#pragma unroll
    for (int i = 0; i < 32; ++i) {
        int g = tid + 256 * i;            // 0..8191
        float f = W[g];
        int row = g >> 7, k = g & 127;
        unsigned short hb = bf16_rne(f);
        sWhi[row * WPAD + k] = hb;
        sWlo[row * WPAD + k] = bf16_rne(f - bf16_tof(hb));
    }

    const int wave = tid >> 6;
    const int l = tid & 63;
    const int lr = l & 15;                // A/B row-in-tile; C/D col
    const int lk = l >> 4;                // k-group / C/D row-group
    const int n0w = blockIdx.x * 64 + wave * 16;

    const int arow = min(n0w + lr, N - 1);   // clamp: garbage rows never stored
    const float* hrow = h + (size_t)arow * IN_DIM;
    short8 ahi[4], alo[4];
#pragma unroll
    for (int ks = 0; ks < 4; ++ks) {
        int k0 = 32 * ks + 8 * lk;
        floatx4 f0 = *(const floatx4*)(hrow + k0);
        floatx4 f1 = *(const floatx4*)(hrow + k0 + 4);
        float fv[8] = {f0.x, f0.y, f0.z, f0.w, f1.x, f1.y, f1.z, f1.w};
#pragma unroll
        for (int j = 0; j < 8; ++j) {
            unsigned short hb = bf16_rne(fv[j]);
            ahi[ks][j] = (short)hb;
            alo[ks][j] = (short)bf16_rne(fv[j] - bf16_tof(hb));
        }
    }
    __syncthreads();

    float ps[4] = {0.f, 0.f, 0.f, 0.f};
    float pd[4] = {0.f, 0.f, 0.f, 0.f};
#pragma unroll
    for (int ct = 0; ct < 4; ++ct) {
        floatx4 acc = (floatx4){0.f, 0.f, 0.f, 0.f};
#pragma unroll
        for (int ks = 0; ks < 4; ++ks) {
            const int boff = (ct * 16 + lr) * WPAD + 32 * ks + 8 * lk;
            short8 bhi = *(const short8*)&sWhi[boff];
            short8 blo = *(const short8*)&sWlo[boff];
            acc = __builtin_amdgcn_mfma_f32_16x16x32_bf16(ahi[ks], bhi, acc, 0, 0, 0);
            acc = __builtin_amdgcn_mfma_f32_16x16x32_bf16(alo[ks], bhi, acc, 0, 0, 0);
            acc = __builtin_amdgcn_mfma_f32_16x16x32_bf16(ahi[ks], blo, acc, 0, 0, 0);
        }
        const float asv = a[ct * 16 + lr];
        const float adv = a[OUT_DIM + ct * 16 + lr];
#pragma unroll
        for (int r = 0; r < 4; ++r) {
            int n = n0w + lk * 4 + r;
            if (n < N)
                z[(size_t)n * OUT_DIM + ct * 16 + lr] = __float2bfloat16(acc[r]);
            ps[r] += acc[r] * asv;
            pd[r] += acc[r] * adv;
        }
    }
#pragma unroll
    for (int r = 0; r < 4; ++r) {
#pragma unroll
        for (int off = 1; off <= 8; off <<= 1) {
            ps[r] += __shfl_xor(ps[r], off);
            pd[r] += __shfl_xor(pd[r], off);
        }
        int n = n0w + lk * 4 + r;
        if (lr == 0 && n < N) {
            s_src[n] = ps[r];
            s_dst[n] = pd[r];
        }
    }
}

// ---------------------------------------------------------------------------
// Phase 1: single-scan LDS binning (R8-proven body; R12: grid=512 WON).
// ---------------------------------------------------------------------------
__global__ __launch_bounds__(256) void k_bin(
    const int* __restrict__ src, const int* __restrict__ dst,
    int* __restrict__ cursor, unsigned* __restrict__ bdata,
    int* __restrict__ bcnt, int* __restrict__ ovfcnt,
    int2* __restrict__ ovf, int E, int NB, int epb)
{
    __shared__ int cell[512];
    const int tid = threadIdx.x;
    for (int i = tid; i < NB; i += 256) cell[i] = 0;
    __syncthreads();

    const int c = blockIdx.x;
    const int e0 = c * epb;
    const int e1 = min(e0 + epb, E);
    const size_t cbase = (size_t)c * NB * CELL_CAP;
    for (int e = e0 + tid; e < e1; e += 256) {
        int d = __builtin_nontemporal_load(&dst[e]);
        int s = __builtin_nontemporal_load(&src[e]);
        int b = d >> NB_SHIFT;
        int slot = atomicAdd(&cell[b], 1);
        if (slot < CELL_CAP) {
            bdata[cbase + (size_t)b * CELL_CAP + slot] =
                ((unsigned)s << NB_SHIFT) |
                (unsigned)(d & ((1 << NB_SHIFT) - 1));
        } else {
            atomicAdd(&cursor[d], SPILL_BIT);
            int op = atomicAdd(ovfcnt, 1);
            if (op < OVF_CAP) ovf[op] = make_int2(s, d);
        }
    }
    __syncthreads();
    for (int b = tid; b < NB; b += 256) bcnt[c * NB + b] = cell[b];
}

// ---------------------------------------------------------------------------
// Phase 2: one block per bucket = sole owner of 256 contiguous nodes (R8).
// ---------------------------------------------------------------------------
__global__ __launch_bounds__(256) void k_fill(
    const unsigned* __restrict__ bdata, const int* __restrict__ bcnt,
    int* __restrict__ cursor, int* __restrict__ ssort,
    int* __restrict__ ovfcnt, int2* __restrict__ ovf,
    int nb1, int NB, int N)
{
    __shared__ int lcur[256];
    const int tid = threadIdx.x;
    lcur[tid] = 0;
    __syncthreads();

    const int b = blockIdx.x;
    const int n0 = b << NB_SHIFT;
    for (int c = tid; c < nb1; c += 256) {
        int cnt = min(bcnt[c * NB + b], CELL_CAP);
        size_t base = ((size_t)c * NB + b) * CELL_CAP;
        for (int j = 0; j < cnt; ++j) {
            unsigned v = bdata[base + j];
            int i = (int)(v & ((1u << NB_SHIFT) - 1));
            int s = (int)(v >> NB_SHIFT);
            int slot = atomicAdd(&lcur[i], 1);
            if (slot < CAP) {
                ssort[(n0 + i) * CAP + slot] = s;
            } else {
                int op = atomicAdd(ovfcnt, 1);
                if (op < OVF_CAP) ovf[op] = make_int2(s, n0 + i);
            }
        }
    }
    __syncthreads();
    int n = n0 + tid;
    if (n < N) {
        int v = lcur[tid];
        if (v) cursor[n] += v;    // sole owner; spill bits preserved
    }
}

// ---------------------------------------------------------------------------
// Fallback scatter (proven R0 82us body) for small workspaces.
// ---------------------------------------------------------------------------
__global__ __launch_bounds__(256) void k_scatter(
    const int* __restrict__ src, const int* __restrict__ dst,
    int* __restrict__ cursor, int* __restrict__ ssort,
    int* __restrict__ ovfcnt, int2* __restrict__ ovf, int E)
{
    const int x = blockIdx.x & 7;
    const int c = blockIdx.x >> 3;
    const int e0 = c * CHUNK;
#pragma unroll
    for (int i = 0; i < CHUNK / 256; ++i) {
        int e = e0 + i * 256 + threadIdx.x;
        if (e < E) {
            int d = __builtin_nontemporal_load(&dst[e]);
            if (OWNER(d) == x) {
                int s = __builtin_nontemporal_load(&src[e]);
                int pos = atomicAdd(&cursor[d], 1);
                if (pos < CAP) {
                    ssort[d * CAP + pos] = s;
                } else {
                    int op = atomicAdd(ovfcnt, 1);
                    if (op < OVF_CAP) ovf[op] = make_int2(s, d);
                }
            }
        }
    }
}

// ---------------------------------------------------------------------------
// Fused per-node softmax + weighted gather + ELU: TWO nodes per wave.
// half = lane>>5 owns node n = blockIdx*8 + wave*2 + half; hl = lane&31.
// Score phase: all 64 lanes active (deg<=32<=32 lanes/half). Shfl sources
// offset by half*32; folds use offsets <32 only (stay within half).
// Empty node: sum=0 -> inv=0 -> out=exp(0)-1=0 (matches elu(0)).
// Ovf adds e2 at hl==0 BEFORE the intra-half sum fold (== old lane-0 order).
// ---------------------------------------------------------------------------
__global__ __launch_bounds__(256) void k_node(
    const int* __restrict__ cursor, const int* __restrict__ ssort,
    const float* __restrict__ s_src, const float* __restrict__ s_dst,
    const int* __restrict__ ovfcnt, const int2* __restrict__ ovf,
    const __hip_bfloat16* __restrict__ z, float* __restrict__ out, int N)
{
    const int lane = threadIdx.x & 63;
    const int wave = threadIdx.x >> 6;
    const int half = lane >> 5;           // node within wave
    const int hl = lane & 31;             // lane within half
    const int lg = (lane >> 4) & 1;       // edge subgroup within half
    const int lc = lane & 15;             // col group: cols 4lc..4lc+3
    const int sbase = half << 5;          // shfl base for this half

    int n = blockIdx.x * 8 + wave * 2 + half;
    const bool valid = n < N;
    n = valid ? n : N - 1;                // clamp; stores are guarded

    const int raw = valid ? cursor[n] : 0;
    const int low = raw & 0xFFFFF;
    const int deg = min(low, CAP);
    const int base = n * CAP;
    const float sdn = s_dst[n];

    // score phase: lane hl handles edge hl of its half's node
    float sum = 0.f;
    int sv = 0;
    float ev = 0.f;
    if (hl < deg) {
        sv = __builtin_nontemporal_load(&ssort[base + hl]);
        float sc = s_src[sv] + sdn;
        sc = sc > 0.f ? sc : 0.01f * sc;  // leaky_relu
        ev = __expf(sc);
    }
    sum = ev;

    // gather: 2 edges/node per load slot; all loads in flight
    floatx4 acc = (floatx4){0.f, 0.f, 0.f, 0.f};
    if (!__any(deg > 16)) {
        int sa[8]; float w[8];
#pragma unroll
        for (int u = 0; u < 8; ++u) {
            int jj = 2 * u + lg;
            bool ok = jj < deg;
            int idx = sbase + (ok ? jj : 0);
            int s = __shfl(sv, idx);
            float ww = __shfl(ev, idx);
            w[u] = ok ? ww : 0.f;
            sa[u] = ok ? s : 0;
        }
        uint2 v[8];
#pragma unroll
        for (int u = 0; u < 8; ++u)
            v[u] = *(const uint2*)&z[(size_t)sa[u] * OUT_DIM + 4 * lc];
#pragma unroll
        for (int u = 0; u < 8; ++u) {
            acc.x += w[u] * __uint_as_float(v[u].x << 16);
            acc.y += w[u] * __uint_as_float(v[u].x & 0xFFFF0000u);
            acc.z += w[u] * __uint_as_float(v[u].y << 16);
            acc.w += w[u] * __uint_as_float(v[u].y & 0xFFFF0000u);
        }
    } else {
        int sa[16]; float w[16];
#pragma unroll
        for (int u = 0; u < 16; ++u) {
            int jj = 2 * u + lg;
            bool ok = jj < deg;
            int idx = sbase + (ok ? jj : 0);
            int s = __shfl(sv, idx);
            float ww = __shfl(ev, idx);
            w[u] = ok ? ww : 0.f;
            sa[u] = ok ? s : 0;
        }
        uint2 v[16];
#pragma unroll
        for (int u = 0; u < 16; ++u)
            v[u] = *(const uint2*)&z[(size_t)sa[u] * OUT_DIM + 4 * lc];
#pragma unroll
        for (int u = 0; u < 16; ++u) {
            acc.x += w[u] * __uint_as_float(v[u].x << 16);
            acc.y += w[u] * __uint_as_float(v[u].x & 0xFFFF0000u);
            acc.z += w[u] * __uint_as_float(v[u].y << 16);
            acc.w += w[u] * __uint_as_float(v[u].y & 0xFFFF0000u);
        }
    }
    // fold the 2 edge subgroups within the half
    acc.x += __shfl_xor(acc.x, 16); acc.y += __shfl_xor(acc.y, 16);
    acc.z += __shfl_xor(acc.z, 16); acc.w += __shfl_xor(acc.w, 16);

    // exact overflow path (per half; acc adds identical across the half's
    // 32 lanes post-fold; sum contribution at hl==0 pre-fold == old order)
    if (raw > CAP) {
        int oc = min(*ovfcnt, OVF_CAP);
        for (int i = 0; i < oc; ++i) {
            int2 p = ovf[i];
            if (p.y == n) {
                float sc = s_src[p.x] + sdn;
                sc = sc > 0.f ? sc : 0.01f * sc;
                float e2 = __expf(sc);
                if (hl == 0) sum += e2;
                uint2 v = *(const uint2*)&z[(size_t)p.x * OUT_DIM + 4 * lc];
                acc.x += e2 * __uint_as_float(v.x << 16);
                acc.y += e2 * __uint_as_float(v.x & 0xFFFF0000u);
                acc.z += e2 * __uint_as_float(v.y << 16);
                acc.w += e2 * __uint_as_float(v.y & 0xFFFF0000u);
            }
        }
    }

    // sum fold within the half (offsets < 32 never cross halves)
#pragma unroll
    for (int off = 16; off >= 1; off >>= 1) sum += __shfl_xor(sum, off);

    if (lg == 0 && valid) {               // lanes 0-15 (half 0), 32-47 (half 1)
        float inv = sum > 0.f ? 1.f / sum : 0.f;   // empty node -> 0
        floatx4 o;
        o.x = acc.x * inv; o.y = acc.y * inv;
        o.z = acc.z * inv; o.w = acc.w * inv;
        o.x = o.x > 0.f ? o.x : __expf(o.x) - 1.f;   // ELU, alpha=1
        o.y = o.y > 0.f ? o.y : __expf(o.y) - 1.f;
        o.z = o.z > 0.f ? o.z : __expf(o.z) - 1.f;
        o.w = o.w > 0.f ? o.w : __expf(o.w) - 1.f;
        __builtin_nontemporal_store(o, (floatx4*)&out[(size_t)n * OUT_DIM + 4 * lc]);
    }
}

// ---------------------------------------------------------------------------
extern "C" void kernel_launch(void* const* d_in, const int* in_sizes, int n_in,
                              void* d_out, int out_size, void* d_ws, size_t ws_size,
                              hipStream_t stream)
{
    (void)n_in; (void)out_size;

    const float* h  = (const float*)d_in[0];
    const int* src  = (const int*)d_in[1];
    const int* dst  = (const int*)d_in[2];
    const float* W  = (const float*)d_in[3];
    const float* a  = (const float*)d_in[4];
    const int N = in_sizes[0] / IN_DIM;
    const int E = in_sizes[1];
    float* out = (float*)d_out;

    const int NB  = (N + (1 << NB_SHIFT) - 1) >> NB_SHIFT;
    const int nb1 = NBIN;                       // 512 = exactly 2 blocks/CU
    const int epb = (E + NBIN - 1) / NBIN;      // edges per bin block

    auto rnd = [](size_t b) { return (b + 255) & ~(size_t)255; };
    // meta: cursor[N] | ovfcnt | bcnt[nb1*NB]  (bcnt fully overwritten by k_bin)
    const size_t meta_ints = (size_t)N + 1 + (size_t)nb1 * NB;
    const size_t need_bucket =
        rnd((size_t)N * OUT_DIM * 2) + 2 * rnd((size_t)N * 4) +
        rnd(meta_ints * 4) + rnd((size_t)OVF_CAP * 8) +
        rnd((size_t)N * CAP * 4) + rnd((size_t)nb1 * NB * CELL_CAP * 4);
    const bool bucketed = (NB <= 512) && (need_bucket <= ws_size);

    char* wsp = (char*)d_ws;
    size_t off = 0;
    auto alloc = [&](size_t bytes) -> void* {
        void* p = wsp + off;
        off = (off + bytes + 255) & ~(size_t)255;
        return p;
    };
    __hip_bfloat16* z = (__hip_bfloat16*)alloc((size_t)N * OUT_DIM * 2);
    float* s_src = (float*)alloc((size_t)N * 4);
    float* s_dst = (float*)alloc((size_t)N * 4);

    if (bucketed) {
        int* cursor = (int*)alloc(meta_ints * 4);
        int* ovfcnt = cursor + N;
        int* bcnt   = cursor + N + 1;
        int2* ovf   = (int2*)alloc((size_t)OVF_CAP * 8);
        int* ssort  = (int*)alloc((size_t)N * CAP * 4);
        unsigned* bdata = (unsigned*)alloc((size_t)nb1 * NB * CELL_CAP * 4);

        // gemm zeroes cursor|ovfcnt (N+1 ints); bcnt fully overwritten by k_bin
        k_gemm<<<(N + 63) / 64, 256, 0, stream>>>(h, W, a, z, s_src, s_dst, N,
                                                  cursor, N + 1);
        k_bin<<<nb1, 256, 0, stream>>>(src, dst, cursor, bdata, bcnt,
                                       ovfcnt, ovf, E, NB, epb);
        k_fill<<<NB, 256, 0, stream>>>(bdata, bcnt, cursor, ssort,
                                       ovfcnt, ovf, nb1, NB, N);
        k_node<<<(N + 7) / 8, 256, 0, stream>>>(cursor, ssort, s_src, s_dst,
                                                ovfcnt, ovf, z, out, N);
    } else {
        int* cursor = (int*)alloc((size_t)(N + 1) * 4);
        int* ovfcnt = cursor + N;
        int2* ovf   = (int2*)alloc((size_t)OVF_CAP * 8);
        int* ssort  = (int*)alloc((size_t)N * CAP * 4);

        const int nchunks = (E + CHUNK - 1) / CHUNK;
        k_gemm<<<(N + 63) / 64, 256, 0, stream>>>(h, W, a, z, s_src, s_dst, N,
                                                  cursor, N + 1);
        k_scatter<<<nchunks * 8, 256, 0, stream>>>(src, dst, cursor, ssort,
                                                   ovfcnt, ovf, E);
        k_node<<<(N + 7) / 8, 256, 0, stream>>>(cursor, ssort, s_src, s_dst,
                                                ovfcnt, ovf, z, out, N);
    }
}